// Round 1
// baseline (686.580 us; speedup 1.0000x reference)
//
#include <hip/hip_runtime.h>
#include <hip/hip_bf16.h>

typedef unsigned short u16;
typedef __attribute__((ext_vector_type(8))) short short8;
typedef __attribute__((ext_vector_type(4))) short short4v;
typedef __attribute__((ext_vector_type(4))) float f32x4;

#define HEADS 20
#define HD 64
#define BB 8
#define SQ 4096
#define HDIM 1280
#define SKV 109
#define CDIM 768
#define SKV_PAD 128
#define SKV_T 112

static __device__ __forceinline__ u16 f2bf(float x) {
  union { __hip_bfloat16 h; u16 u; } cv;
  cv.h = __float2bfloat16(x);
  return cv.u;
}

// ---- prep: out[n][k] = bf16(W[k][n] * scale)  (W is K x N row-major)
__global__ __launch_bounds__(256) void tcvt(const float* __restrict__ W,
                                            u16* __restrict__ out, int K, int N,
                                            float scale) {
  __shared__ float t[32][33];
  int tx = threadIdx.x & 31, ty = threadIdx.x >> 5;
  int n0 = blockIdx.x * 32, k0 = blockIdx.y * 32;
#pragma unroll
  for (int i = 0; i < 32; i += 8)
    t[ty + i][tx] = W[(size_t)(k0 + ty + i) * N + n0 + tx];
  __syncthreads();
#pragma unroll
  for (int i = 0; i < 32; i += 8)
    out[(size_t)(n0 + ty + i) * K + k0 + tx] = f2bf(t[tx][ty + i] * scale);
}

// ---- prep: encoder states f32 (8,109,768) -> bf16 (8,128,768), zero pad rows
__global__ __launch_bounds__(256) void ehs_prep(const float* __restrict__ e,
                                                u16* __restrict__ out) {
  int idx = blockIdx.x * 256 + threadIdx.x;
  if (idx >= BB * SKV_PAD * CDIM / 4) return;
  int c4 = idx * 4;
  int b = c4 / (SKV_PAD * CDIM);
  int rem = c4 - b * (SKV_PAD * CDIM);
  int s = rem / CDIM;
  int c = rem - s * CDIM;
  short4v o = {0, 0, 0, 0};
  if (s < SKV) {
    f32x4 v = *(const f32x4*)(e + ((size_t)b * SKV + s) * CDIM + c);
#pragma unroll
    for (int j = 0; j < 4; j++) o[j] = (short)f2bf(v[j]);
  }
  *(short4v*)&out[c4] = o;
}

// ---- 128x128 tile GEMM: C = A(MxK) @ Bt(NxK)^T, bf16 MFMA, f32 acc.
// A: f32 or bf16 row-major. Bt: bf16 N x K row-major (pre-transposed weight).
// MODE 0: bf16 row-major out. 1: K-heads layout. 2: V^T layout. 3: f32 + bias + residual.
template <typename AT, int MODE>
__global__ __launch_bounds__(256, 2)
void gemm128(const AT* __restrict__ A, const u16* __restrict__ Bt,
             void* __restrict__ outp, int M, int N, int K,
             const float* __restrict__ bias, const float* __restrict__ resid) {
  __shared__ u16 Alds[128 * 40];  // stride 40 (32 data + 8 pad) -> 2-way banks (free)
  __shared__ u16 Blds[128 * 40];
  const int tid = threadIdx.x;
  const int wid = tid >> 6, lane = tid & 63;
  const int wm = wid >> 1, wn = wid & 1;
  const int g = lane >> 4, r = lane & 15;
  const int row0 = blockIdx.x * 128;
  const int col0 = blockIdx.y * 128;
  const int srow = tid >> 1, sseg = tid & 1;

  f32x4 acc[4][4] = {};

  for (int kt = 0; kt < K; kt += 32) {
    // stage A tile 128x32
    if constexpr (sizeof(AT) == 4) {
      const float* ap = (const float*)A + (size_t)(row0 + srow) * K + kt + sseg * 16;
      f32x4 v0 = *(const f32x4*)(ap + 0);
      f32x4 v1 = *(const f32x4*)(ap + 4);
      f32x4 v2 = *(const f32x4*)(ap + 8);
      f32x4 v3 = *(const f32x4*)(ap + 12);
      short8 p0, p1;
#pragma unroll
      for (int j = 0; j < 4; j++) {
        p0[j]     = (short)f2bf(v0[j]);
        p0[j + 4] = (short)f2bf(v1[j]);
        p1[j]     = (short)f2bf(v2[j]);
        p1[j + 4] = (short)f2bf(v3[j]);
      }
      *(short8*)&Alds[srow * 40 + sseg * 16]     = p0;
      *(short8*)&Alds[srow * 40 + sseg * 16 + 8] = p1;
    } else {
      const u16* ap = (const u16*)A + (size_t)(row0 + srow) * K + kt + sseg * 16;
      *(short8*)&Alds[srow * 40 + sseg * 16]     = *(const short8*)(ap);
      *(short8*)&Alds[srow * 40 + sseg * 16 + 8] = *(const short8*)(ap + 8);
    }
    // stage B tile 128x32 (bf16)
    {
      const u16* bp = Bt + (size_t)(col0 + srow) * K + kt + sseg * 16;
      *(short8*)&Blds[srow * 40 + sseg * 16]     = *(const short8*)(bp);
      *(short8*)&Blds[srow * 40 + sseg * 16 + 8] = *(const short8*)(bp + 8);
    }
    __syncthreads();
    short8 afr[4], bfr[4];
#pragma unroll
    for (int mi = 0; mi < 4; mi++)
      afr[mi] = *(short8*)&Alds[(wm * 64 + mi * 16 + r) * 40 + g * 8];
#pragma unroll
    for (int ni = 0; ni < 4; ni++)
      bfr[ni] = *(short8*)&Blds[(wn * 64 + ni * 16 + r) * 40 + g * 8];
#pragma unroll
    for (int mi = 0; mi < 4; mi++)
#pragma unroll
      for (int ni = 0; ni < 4; ni++)
        acc[mi][ni] = __builtin_amdgcn_mfma_f32_16x16x32_bf16(afr[mi], bfr[ni],
                                                              acc[mi][ni], 0, 0, 0);
    __syncthreads();
  }

  // epilogue: D row = (lane>>4)*4 + i, col = lane&15 (m89-verified layout)
  if constexpr (MODE == 0) {
    u16* O = (u16*)outp;
#pragma unroll
    for (int mi = 0; mi < 4; mi++)
#pragma unroll
      for (int i = 0; i < 4; i++) {
        size_t m = row0 + wm * 64 + mi * 16 + g * 4 + i;
        size_t base = m * N + col0 + wn * 64 + r;
#pragma unroll
        for (int ni = 0; ni < 4; ni++)
          O[base + ni * 16] = f2bf(acc[mi][ni][i]);
      }
  } else if constexpr (MODE == 1 || MODE == 2) {
    u16* O = (u16*)outp;
#pragma unroll
    for (int mi = 0; mi < 4; mi++)
#pragma unroll
      for (int i = 0; i < 4; i++) {
        int m = row0 + wm * 64 + mi * 16 + g * 4 + i;
        int b = m >> 7, skv = m & 127;
#pragma unroll
        for (int ni = 0; ni < 4; ni++) {
          int col = col0 + wn * 64 + ni * 16 + r;
          int hh = col >> 6, d = col & 63;
          size_t addr;
          if constexpr (MODE == 1)
            addr = (((size_t)b * HEADS + hh) * SKV_PAD + skv) * HD + d;
          else
            addr = (((size_t)b * HEADS + hh) * HD + d) * SKV_PAD + skv;
          O[addr] = f2bf(acc[mi][ni][i]);
        }
      }
  } else {
    float* O = (float*)outp;
#pragma unroll
    for (int mi = 0; mi < 4; mi++)
#pragma unroll
      for (int i = 0; i < 4; i++) {
        size_t m = row0 + wm * 64 + mi * 16 + g * 4 + i;
        size_t base = m * N + col0 + wn * 64 + r;
#pragma unroll
        for (int ni = 0; ni < 4; ni++) {
          int col = col0 + wn * 64 + ni * 16 + r;
          O[base + ni * 16] = acc[mi][ni][i] + bias[col] + resid[base + ni * 16];
        }
      }
  }
}

// ---- fused attention: per block = 64 q-rows of one (b,h); 4 waves x 16 rows.
__global__ __launch_bounds__(256, 2)
void attn_kernel(const u16* __restrict__ q, const u16* __restrict__ kh,
                 const u16* __restrict__ vt, u16* __restrict__ o) {
  __shared__ u16 Klds[SKV_T * 72];    // [skv 112][d 64+8 pad]
  __shared__ u16 Vlds[HD * 136];      // [d 64][skv 128+8 pad]
  __shared__ u16 Plds[4 * 16 * 136];  // per-wave P [16][128+8]
  const int tid = threadIdx.x;
  const int wid = tid >> 6, lane = tid & 63;
  const int g = lane >> 4, r = lane & 15;
  const int qt = blockIdx.x;
  const int bh = blockIdx.y;
  const int b = bh / HEADS, h = bh - b * HEADS;

  const u16* kg = kh + (size_t)bh * SKV_PAD * HD;
  for (int i = tid; i < SKV_T * 8; i += 256) {
    int row = i >> 3, c = (i & 7) * 8;
    *(short8*)&Klds[row * 72 + c] = *(const short8*)(kg + row * HD + c);
  }
  const u16* vg = vt + (size_t)bh * HD * SKV_PAD;
  for (int i = tid; i < HD * 16; i += 256) {
    int row = i >> 4, c = (i & 15) * 8;
    *(short8*)&Vlds[row * 136 + c] = *(const short8*)(vg + row * SKV_PAD + c);
  }
  __syncthreads();

  // Q fragments straight from global (scale 1/8 folded into Wq)
  const u16* qg = q + ((size_t)b * SQ + qt * 64 + wid * 16 + r) * HDIM + h * HD + g * 8;
  short8 aq0 = *(const short8*)(qg);
  short8 aq1 = *(const short8*)(qg + 32);

  f32x4 s[7];
#pragma unroll
  for (int nf = 0; nf < 7; nf++) {
    f32x4 z = {0.f, 0.f, 0.f, 0.f};
    short8 k0 = *(short8*)&Klds[(nf * 16 + r) * 72 + g * 8];
    short8 k1 = *(short8*)&Klds[(nf * 16 + r) * 72 + 32 + g * 8];
    z = __builtin_amdgcn_mfma_f32_16x16x32_bf16(aq0, k0, z, 0, 0, 0);
    z = __builtin_amdgcn_mfma_f32_16x16x32_bf16(aq1, k1, z, 0, 0, 0);
    s[nf] = z;
  }

  // zero pad columns 112..127 of this wave's P tile
  {
    short4v z = {0, 0, 0, 0};
    *(short4v*)&Plds[(wid * 16 + r) * 136 + 112 + g * 4] = z;
  }

  // wave-parallel softmax: row (g*4+i) spread over 16 lanes x 7 frags
#pragma unroll
  for (int i = 0; i < 4; i++) {
    float pv[7];
    float mx = -1e30f;
#pragma unroll
    for (int nf = 0; nf < 7; nf++) {
      float v = s[nf][i];
      if (nf == 6 && r >= 13) v = -1e30f;  // cols >= 109 masked
      pv[nf] = v;
      mx = fmaxf(mx, v);
    }
#pragma unroll
    for (int d = 1; d < 16; d <<= 1) mx = fmaxf(mx, __shfl_xor(mx, d, 64));
    float sum = 0.f;
#pragma unroll
    for (int nf = 0; nf < 7; nf++) {
      float e = (nf == 6 && r >= 13) ? 0.f : __expf(pv[nf] - mx);
      pv[nf] = e;
      sum += e;
    }
#pragma unroll
    for (int d = 1; d < 16; d <<= 1) sum += __shfl_xor(sum, d, 64);
    float is = 1.f / sum;
#pragma unroll
    for (int nf = 0; nf < 7; nf++)
      Plds[(wid * 16 + g * 4 + i) * 136 + nf * 16 + r] = f2bf(pv[nf] * is);
  }
  __syncthreads();

  f32x4 oacc[4] = {};
#pragma unroll
  for (int kk = 0; kk < 4; kk++) {
    short8 ap = *(short8*)&Plds[(wid * 16 + r) * 136 + kk * 32 + g * 8];
#pragma unroll
    for (int nf = 0; nf < 4; nf++) {
      short8 bv = *(short8*)&Vlds[(nf * 16 + r) * 136 + kk * 32 + g * 8];
      oacc[nf] = __builtin_amdgcn_mfma_f32_16x16x32_bf16(ap, bv, oacc[nf], 0, 0, 0);
    }
  }
  u16* og = o + ((size_t)b * SQ + qt * 64 + wid * 16) * HDIM + h * HD;
#pragma unroll
  for (int nf = 0; nf < 4; nf++)
#pragma unroll
    for (int i = 0; i < 4; i++)
      og[(size_t)(g * 4 + i) * HDIM + nf * 16 + r] = f2bf(oacc[nf][i]);
}

extern "C" void kernel_launch(void* const* d_in, const int* in_sizes, int n_in,
                              void* d_out, int out_size, void* d_ws, size_t ws_size,
                              hipStream_t stream) {
  const float* hs  = (const float*)d_in[0];
  const float* ehs = (const float*)d_in[1];
  const float* Wq  = (const float*)d_in[2];
  const float* Wk  = (const float*)d_in[3];
  const float* Wv  = (const float*)d_in[4];
  const float* Wo  = (const float*)d_in[5];
  const float* bo  = (const float*)d_in[6];

  char* ws = (char*)d_ws;
  size_t off = 0;
  auto alloc = [&](size_t elems) {
    u16* p = (u16*)(ws + off);
    off += ((elems * 2 + 255) / 256) * 256;
    return p;
  };
  u16* wqt  = alloc((size_t)HDIM * HDIM);
  u16* wot  = alloc((size_t)HDIM * HDIM);
  u16* wkt  = alloc((size_t)HDIM * CDIM);
  u16* wvt  = alloc((size_t)HDIM * CDIM);
  u16* ehsp = alloc((size_t)BB * SKV_PAD * CDIM);
  u16* khb  = alloc((size_t)BB * HEADS * SKV_PAD * HD);
  u16* vtb  = alloc((size_t)BB * HEADS * HD * SKV_PAD);
  u16* qb   = alloc((size_t)BB * SQ * HDIM);
  u16* ao   = alloc((size_t)BB * SQ * HDIM);

  // prep: weight transposes (scale 1/sqrt(64) folded into Wq), encoder pad
  tcvt<<<dim3(HDIM / 32, HDIM / 32), 256, 0, stream>>>(Wq, wqt, HDIM, HDIM, 0.125f);
  tcvt<<<dim3(HDIM / 32, CDIM / 32), 256, 0, stream>>>(Wk, wkt, CDIM, HDIM, 1.0f);
  tcvt<<<dim3(HDIM / 32, CDIM / 32), 256, 0, stream>>>(Wv, wvt, CDIM, HDIM, 1.0f);
  tcvt<<<dim3(HDIM / 32, HDIM / 32), 256, 0, stream>>>(Wo, wot, HDIM, HDIM, 1.0f);
  ehs_prep<<<dim3((BB * SKV_PAD * CDIM / 4 + 255) / 256), 256, 0, stream>>>(ehs, ehsp);

  // K,V projections (M=1024 padded rows)
  gemm128<u16, 1><<<dim3(8, 10), 256, 0, stream>>>(ehsp, wkt, khb, BB * SKV_PAD,
                                                   HDIM, CDIM, nullptr, nullptr);
  gemm128<u16, 2><<<dim3(8, 10), 256, 0, stream>>>(ehsp, wvt, vtb, BB * SKV_PAD,
                                                   HDIM, CDIM, nullptr, nullptr);
  // Q projection (f32 A staged+converted in-kernel)
  gemm128<float, 0><<<dim3(256, 10), 256, 0, stream>>>(hs, wqt, qb, BB * SQ, HDIM,
                                                       HDIM, nullptr, nullptr);
  // attention
  attn_kernel<<<dim3(SQ / 64, BB * HEADS), 256, 0, stream>>>(qb, khb, vtb, ao);
  // output projection + bias + residual
  gemm128<u16, 3><<<dim3(256, 10), 256, 0, stream>>>(ao, wot, (void*)d_out, BB * SQ,
                                                     HDIM, HDIM, bo, hs);
}

// Round 2
// 542.661 us; speedup vs baseline: 1.2652x; 1.2652x over previous
//
#include <hip/hip_runtime.h>
#include <hip/hip_bf16.h>

typedef unsigned short u16;
typedef __attribute__((ext_vector_type(8))) short short8;
typedef __attribute__((ext_vector_type(4))) short short4v;
typedef __attribute__((ext_vector_type(4))) float f32x4;

#define HEADS 20
#define HD 64
#define BB 8
#define SQ 4096
#define HDIM 1280
#define SKV 109
#define CDIM 768
#define SKV_PAD 128
#define SKV_T 112

static __device__ __forceinline__ u16 f2bf(float x) {
  union { __hip_bfloat16 h; u16 u; } cv;
  cv.h = __float2bfloat16(x);
  return cv.u;
}

// async global->LDS, 16B per lane. LDS dest must be wave-uniform base + lane*16
// (our staging map is exactly linear in lane, so this holds).
static __device__ __forceinline__ void gll16(const void* g, void* l) {
  __builtin_amdgcn_global_load_lds(
      (const __attribute__((address_space(1))) unsigned int*)g,
      (__attribute__((address_space(3))) unsigned int*)l, 16, 0, 0);
}

// ---- prep: out[n][k] = bf16(W[k][n] * scale)  (W is K x N row-major)
__global__ __launch_bounds__(256) void tcvt(const float* __restrict__ W,
                                            u16* __restrict__ out, int K, int N,
                                            float scale) {
  __shared__ float t[32][33];
  int tx = threadIdx.x & 31, ty = threadIdx.x >> 5;
  int n0 = blockIdx.x * 32, k0 = blockIdx.y * 32;
#pragma unroll
  for (int i = 0; i < 32; i += 8)
    t[ty + i][tx] = W[(size_t)(k0 + ty + i) * N + n0 + tx];
  __syncthreads();
#pragma unroll
  for (int i = 0; i < 32; i += 8)
    out[(size_t)(n0 + ty + i) * K + k0 + tx] = f2bf(t[tx][ty + i] * scale);
}

// ---- prep: encoder states f32 (8,109,768) -> bf16 (8,128,768), zero pad rows
__global__ __launch_bounds__(256) void ehs_prep(const float* __restrict__ e,
                                                u16* __restrict__ out) {
  int idx = blockIdx.x * 256 + threadIdx.x;
  if (idx >= BB * SKV_PAD * CDIM / 4) return;
  int c4 = idx * 4;
  int b = c4 / (SKV_PAD * CDIM);
  int rem = c4 - b * (SKV_PAD * CDIM);
  int s = rem / CDIM;
  int c = rem - s * CDIM;
  short4v o = {0, 0, 0, 0};
  if (s < SKV) {
    f32x4 v = *(const f32x4*)(e + ((size_t)b * SKV + s) * CDIM + c);
#pragma unroll
    for (int j = 0; j < 4; j++) o[j] = (short)f2bf(v[j]);
  }
  *(short4v*)&out[c4] = o;
}

// ---- prep: hidden_states f32 -> bf16 (vectorized 8/thread, grid-stride)
__global__ __launch_bounds__(256) void hscvt(const float* __restrict__ in,
                                             u16* __restrict__ out) {
  const size_t total = (size_t)BB * SQ * HDIM;
  size_t step = (size_t)gridDim.x * 256 * 8;
  for (size_t i = ((size_t)blockIdx.x * 256 + threadIdx.x) * 8; i < total;
       i += step) {
    f32x4 a = *(const f32x4*)(in + i);
    f32x4 b = *(const f32x4*)(in + i + 4);
    short8 o;
#pragma unroll
    for (int j = 0; j < 4; j++) {
      o[j] = (short)f2bf(a[j]);
      o[j + 4] = (short)f2bf(b[j]);
    }
    *(short8*)&out[i] = o;
  }
}

// ---- m97-structure GEMM: C = A(Mx K) @ Bt(N x K)^T, bf16 MFMA, f32 acc.
// 128x128 tile, BK=32, linear LDS + global_load_lds dwordx4 staging.
// N fixed = HDIM. 1D grid with XCD-bijective swizzle (grid % 8 == 0).
// MODE 0: bf16 row-major out. 1: K-heads layout. 2: V^T layout.
// MODE 3: f32 out + bias + residual.
template <int MODE>
__global__ __launch_bounds__(256)
void gemm_glds(const u16* __restrict__ A, const u16* __restrict__ Bt,
               void* __restrict__ outp, int K, int ntn,
               const float* __restrict__ bias, const float* __restrict__ resid) {
  __shared__ u16 Alds[128 * 32];
  __shared__ u16 Blds[128 * 32];
  const int tid = threadIdx.x;
  const int wid = tid >> 6, lane = tid & 63;
  const int wm = wid >> 1, wn = wid & 1;
  const int g = lane >> 4, r = lane & 15;

  const int nwg = gridDim.x;
  const int orig = blockIdx.x;
  const int wg = (orig & 7) * (nwg >> 3) + (orig >> 3);  // XCD swizzle (m157)
  const int mt = wg / ntn, nt = wg - mt * ntn;
  const int row0 = mt * 128, col0 = nt * 128;

  // staging map: thread t covers elements [t*8, t*8+8) of each 2048-elem half
  const int erow = tid >> 2, ecol = (tid & 3) * 8;

  f32x4 acc[4][4] = {};

  for (int kt = 0; kt < K; kt += 32) {
    const u16* ag = A + (size_t)(row0 + erow) * K + kt + ecol;
    const u16* bg = Bt + (size_t)(col0 + erow) * K + kt + ecol;
    gll16(ag, &Alds[erow * 32 + ecol]);
    gll16(ag + (size_t)64 * K, &Alds[(erow + 64) * 32 + ecol]);
    gll16(bg, &Blds[erow * 32 + ecol]);
    gll16(bg + (size_t)64 * K, &Blds[(erow + 64) * 32 + ecol]);
    __syncthreads();  // drains vmcnt (global_load_lds) + barrier

    short8 afr[4], bfr[4];
#pragma unroll
    for (int mi = 0; mi < 4; mi++)
      afr[mi] = *(short8*)&Alds[(wm * 64 + mi * 16 + r) * 32 + g * 8];
#pragma unroll
    for (int ni = 0; ni < 4; ni++)
      bfr[ni] = *(short8*)&Blds[(wn * 64 + ni * 16 + r) * 32 + g * 8];
#pragma unroll
    for (int mi = 0; mi < 4; mi++)
#pragma unroll
      for (int ni = 0; ni < 4; ni++)
        acc[mi][ni] = __builtin_amdgcn_mfma_f32_16x16x32_bf16(afr[mi], bfr[ni],
                                                              acc[mi][ni], 0, 0, 0);
    __syncthreads();
  }

  // epilogue: D row = (lane>>4)*4 + i, col = lane&15 (m89-verified layout)
  if constexpr (MODE == 0) {
    u16* O = (u16*)outp;
#pragma unroll
    for (int mi = 0; mi < 4; mi++)
#pragma unroll
      for (int i = 0; i < 4; i++) {
        size_t m = row0 + wm * 64 + mi * 16 + g * 4 + i;
        size_t base = m * HDIM + col0 + wn * 64 + r;
#pragma unroll
        for (int ni = 0; ni < 4; ni++)
          O[base + ni * 16] = f2bf(acc[mi][ni][i]);
      }
  } else if constexpr (MODE == 1 || MODE == 2) {
    u16* O = (u16*)outp;
#pragma unroll
    for (int mi = 0; mi < 4; mi++)
#pragma unroll
      for (int i = 0; i < 4; i++) {
        int m = row0 + wm * 64 + mi * 16 + g * 4 + i;
        int b = m >> 7, skv = m & 127;
#pragma unroll
        for (int ni = 0; ni < 4; ni++) {
          int col = col0 + wn * 64 + ni * 16 + r;
          int hh = col >> 6, d = col & 63;
          size_t addr;
          if constexpr (MODE == 1)
            addr = (((size_t)b * HEADS + hh) * SKV_PAD + skv) * HD + d;
          else
            addr = (((size_t)b * HEADS + hh) * HD + d) * SKV_PAD + skv;
          O[addr] = f2bf(acc[mi][ni][i]);
        }
      }
  } else {
    float* O = (float*)outp;
#pragma unroll
    for (int mi = 0; mi < 4; mi++)
#pragma unroll
      for (int i = 0; i < 4; i++) {
        size_t m = row0 + wm * 64 + mi * 16 + g * 4 + i;
        size_t base = m * HDIM + col0 + wn * 64 + r;
#pragma unroll
        for (int ni = 0; ni < 4; ni++) {
          int col = col0 + wn * 64 + ni * 16 + r;
          O[base + ni * 16] = acc[mi][ni][i] + bias[col] + resid[base + ni * 16];
        }
      }
  }
}

// ---- fused attention: per block = 64 q-rows of one (b,h); 4 waves x 16 rows.
__global__ __launch_bounds__(256, 2)
void attn_kernel(const u16* __restrict__ q, const u16* __restrict__ kh,
                 const u16* __restrict__ vt, u16* __restrict__ o) {
  __shared__ u16 Klds[SKV_T * 72];    // [skv 112][d 64+8 pad]
  __shared__ u16 Vlds[HD * 136];      // [d 64][skv 128+8 pad]
  __shared__ u16 Plds[4 * 16 * 136];  // per-wave P [16][128+8]
  const int tid = threadIdx.x;
  const int wid = tid >> 6, lane = tid & 63;
  const int g = lane >> 4, r = lane & 15;
  const int qt = blockIdx.x;
  const int bh = blockIdx.y;
  const int b = bh / HEADS, h = bh - b * HEADS;

  const u16* kg = kh + (size_t)bh * SKV_PAD * HD;
  for (int i = tid; i < SKV_T * 8; i += 256) {
    int row = i >> 3, c = (i & 7) * 8;
    *(short8*)&Klds[row * 72 + c] = *(const short8*)(kg + row * HD + c);
  }
  const u16* vg = vt + (size_t)bh * HD * SKV_PAD;
  for (int i = tid; i < HD * 16; i += 256) {
    int row = i >> 4, c = (i & 15) * 8;
    *(short8*)&Vlds[row * 136 + c] = *(const short8*)(vg + row * SKV_PAD + c);
  }
  __syncthreads();

  // Q fragments straight from global (scale 1/8 folded into Wq)
  const u16* qg = q + ((size_t)b * SQ + qt * 64 + wid * 16 + r) * HDIM + h * HD + g * 8;
  short8 aq0 = *(const short8*)(qg);
  short8 aq1 = *(const short8*)(qg + 32);

  f32x4 s[7];
#pragma unroll
  for (int nf = 0; nf < 7; nf++) {
    f32x4 z = {0.f, 0.f, 0.f, 0.f};
    short8 k0 = *(short8*)&Klds[(nf * 16 + r) * 72 + g * 8];
    short8 k1 = *(short8*)&Klds[(nf * 16 + r) * 72 + 32 + g * 8];
    z = __builtin_amdgcn_mfma_f32_16x16x32_bf16(aq0, k0, z, 0, 0, 0);
    z = __builtin_amdgcn_mfma_f32_16x16x32_bf16(aq1, k1, z, 0, 0, 0);
    s[nf] = z;
  }

  // zero pad columns 112..127 of this wave's P tile
  {
    short4v z = {0, 0, 0, 0};
    *(short4v*)&Plds[(wid * 16 + r) * 136 + 112 + g * 4] = z;
  }

  // wave-parallel softmax: row (g*4+i) spread over 16 lanes x 7 frags
#pragma unroll
  for (int i = 0; i < 4; i++) {
    float pv[7];
    float mx = -1e30f;
#pragma unroll
    for (int nf = 0; nf < 7; nf++) {
      float v = s[nf][i];
      if (nf == 6 && r >= 13) v = -1e30f;  // cols >= 109 masked
      pv[nf] = v;
      mx = fmaxf(mx, v);
    }
#pragma unroll
    for (int d = 1; d < 16; d <<= 1) mx = fmaxf(mx, __shfl_xor(mx, d, 64));
    float sum = 0.f;
#pragma unroll
    for (int nf = 0; nf < 7; nf++) {
      float e = (nf == 6 && r >= 13) ? 0.f : __expf(pv[nf] - mx);
      pv[nf] = e;
      sum += e;
    }
#pragma unroll
    for (int d = 1; d < 16; d <<= 1) sum += __shfl_xor(sum, d, 64);
    float is = 1.f / sum;
#pragma unroll
    for (int nf = 0; nf < 7; nf++)
      Plds[(wid * 16 + g * 4 + i) * 136 + nf * 16 + r] = f2bf(pv[nf] * is);
  }
  __syncthreads();

  f32x4 oacc[4] = {};
#pragma unroll
  for (int kk = 0; kk < 4; kk++) {
    short8 ap = *(short8*)&Plds[(wid * 16 + r) * 136 + kk * 32 + g * 8];
#pragma unroll
    for (int nf = 0; nf < 4; nf++) {
      short8 bv = *(short8*)&Vlds[(nf * 16 + r) * 136 + kk * 32 + g * 8];
      oacc[nf] = __builtin_amdgcn_mfma_f32_16x16x32_bf16(ap, bv, oacc[nf], 0, 0, 0);
    }
  }
  u16* og = o + ((size_t)b * SQ + qt * 64 + wid * 16) * HDIM + h * HD;
#pragma unroll
  for (int nf = 0; nf < 4; nf++)
#pragma unroll
    for (int i = 0; i < 4; i++)
      og[(size_t)(g * 4 + i) * HDIM + nf * 16 + r] = f2bf(oacc[nf][i]);
}

extern "C" void kernel_launch(void* const* d_in, const int* in_sizes, int n_in,
                              void* d_out, int out_size, void* d_ws, size_t ws_size,
                              hipStream_t stream) {
  const float* hs  = (const float*)d_in[0];
  const float* ehs = (const float*)d_in[1];
  const float* Wq  = (const float*)d_in[2];
  const float* Wk  = (const float*)d_in[3];
  const float* Wv  = (const float*)d_in[4];
  const float* Wo  = (const float*)d_in[5];
  const float* bo  = (const float*)d_in[6];

  char* ws = (char*)d_ws;
  size_t off = 0;
  auto alloc = [&](size_t elems) {
    u16* p = (u16*)(ws + off);
    off += ((elems * 2 + 255) / 256) * 256;
    return p;
  };
  u16* wqt  = alloc((size_t)HDIM * HDIM);
  u16* wot  = alloc((size_t)HDIM * HDIM);
  u16* wkt  = alloc((size_t)HDIM * CDIM);
  u16* wvt  = alloc((size_t)HDIM * CDIM);
  u16* ehsp = alloc((size_t)BB * SKV_PAD * CDIM);
  u16* khb  = alloc((size_t)BB * HEADS * SKV_PAD * HD);
  u16* vtb  = alloc((size_t)BB * HEADS * HD * SKV_PAD);
  u16* qb   = alloc((size_t)BB * SQ * HDIM);
  u16* ao   = alloc((size_t)BB * SQ * HDIM);
  u16* hsb  = ao;  // alias: hsb dead before attention writes ao

  // prep: weight transposes (1/sqrt(64) folded into Wq), encoder pad, hs->bf16
  tcvt<<<dim3(HDIM / 32, HDIM / 32), 256, 0, stream>>>(Wq, wqt, HDIM, HDIM, 0.125f);
  tcvt<<<dim3(HDIM / 32, CDIM / 32), 256, 0, stream>>>(Wk, wkt, CDIM, HDIM, 1.0f);
  tcvt<<<dim3(HDIM / 32, CDIM / 32), 256, 0, stream>>>(Wv, wvt, CDIM, HDIM, 1.0f);
  tcvt<<<dim3(HDIM / 32, HDIM / 32), 256, 0, stream>>>(Wo, wot, HDIM, HDIM, 1.0f);
  ehs_prep<<<dim3((BB * SKV_PAD * CDIM / 4 + 255) / 256), 256, 0, stream>>>(ehs, ehsp);
  hscvt<<<dim3(2048), 256, 0, stream>>>(hs, hsb);

  // K,V projections (M = 1024 padded rows; grid 80 % 8 == 0)
  gemm_glds<1><<<dim3(80), 256, 0, stream>>>(ehsp, wkt, khb, CDIM, 10, nullptr, nullptr);
  gemm_glds<2><<<dim3(80), 256, 0, stream>>>(ehsp, wvt, vtb, CDIM, 10, nullptr, nullptr);
  // Q projection (bf16 A; grid 2560 % 8 == 0)
  gemm_glds<0><<<dim3(2560), 256, 0, stream>>>(hsb, wqt, qb, HDIM, 10, nullptr, nullptr);
  // attention
  attn_kernel<<<dim3(SQ / 64, BB * HEADS), 256, 0, stream>>>(qb, khb, vtb, ao);
  // output projection + bias + f32 residual
  gemm_glds<3><<<dim3(2560), 256, 0, stream>>>(ao, wot, (void*)d_out, HDIM, 10, bo, hs);
}

// Round 3
// 486.689 us; speedup vs baseline: 1.4107x; 1.1150x over previous
//
#include <hip/hip_runtime.h>
#include <hip/hip_bf16.h>

typedef unsigned short u16;
typedef __attribute__((ext_vector_type(8))) short short8;
typedef __attribute__((ext_vector_type(4))) short short4v;
typedef __attribute__((ext_vector_type(4))) float f32x4;

#define HEADS 20
#define HD 64
#define BB 8
#define SQ 4096
#define HDIM 1280
#define SKV 109
#define CDIM 768
#define SKV_PAD 128
#define SKV_T 112

static __device__ __forceinline__ u16 f2bf(float x) {
  union { __hip_bfloat16 h; u16 u; } cv;
  cv.h = __float2bfloat16(x);
  return cv.u;
}

// async global->LDS, 16B per lane. LDS dest must be wave-uniform base + lane*16
// (our staging map is exactly linear in lane, so this holds).
static __device__ __forceinline__ void gll16(const void* g, void* l) {
  __builtin_amdgcn_global_load_lds(
      (const __attribute__((address_space(1))) unsigned int*)g,
      (__attribute__((address_space(3))) unsigned int*)l, 16, 0, 0);
}

// ---- prep: out[n][k] = bf16(W[k][n] * scale)  (W is K x N row-major)
__global__ __launch_bounds__(256) void tcvt(const float* __restrict__ W,
                                            u16* __restrict__ out, int K, int N,
                                            float scale) {
  __shared__ float t[32][33];
  int tx = threadIdx.x & 31, ty = threadIdx.x >> 5;
  int n0 = blockIdx.x * 32, k0 = blockIdx.y * 32;
#pragma unroll
  for (int i = 0; i < 32; i += 8)
    t[ty + i][tx] = W[(size_t)(k0 + ty + i) * N + n0 + tx];
  __syncthreads();
#pragma unroll
  for (int i = 0; i < 32; i += 8)
    out[(size_t)(n0 + ty + i) * K + k0 + tx] = f2bf(t[tx][ty + i] * scale);
}

// ---- prep: encoder states f32 (8,109,768) -> bf16 (8,128,768), zero pad rows
__global__ __launch_bounds__(256) void ehs_prep(const float* __restrict__ e,
                                                u16* __restrict__ out) {
  int idx = blockIdx.x * 256 + threadIdx.x;
  if (idx >= BB * SKV_PAD * CDIM / 4) return;
  int c4 = idx * 4;
  int b = c4 / (SKV_PAD * CDIM);
  int rem = c4 - b * (SKV_PAD * CDIM);
  int s = rem / CDIM;
  int c = rem - s * CDIM;
  short4v o = {0, 0, 0, 0};
  if (s < SKV) {
    f32x4 v = *(const f32x4*)(e + ((size_t)b * SKV + s) * CDIM + c);
#pragma unroll
    for (int j = 0; j < 4; j++) o[j] = (short)f2bf(v[j]);
  }
  *(short4v*)&out[c4] = o;
}

// ---- prep: hidden_states f32 -> bf16 (vectorized 8/thread, grid-stride)
__global__ __launch_bounds__(256) void hscvt(const float* __restrict__ in,
                                             u16* __restrict__ out) {
  const size_t total = (size_t)BB * SQ * HDIM;
  size_t step = (size_t)gridDim.x * 256 * 8;
  for (size_t i = ((size_t)blockIdx.x * 256 + threadIdx.x) * 8; i < total;
       i += step) {
    f32x4 a = *(const f32x4*)(in + i);
    f32x4 b = *(const f32x4*)(in + i + 4);
    short8 o;
#pragma unroll
    for (int j = 0; j < 4; j++) {
      o[j] = (short)f2bf(a[j]);
      o[j + 4] = (short)f2bf(b[j]);
    }
    *(short8*)&out[i] = o;
  }
}

// ---- m97-structure GEMM: C = A(M x K) @ Bt(N x K)^T, bf16 MFMA, f32 acc.
// 128x128 tile, BK=32, linear LDS + global_load_lds dwordx4 staging.
// __launch_bounds__(256,4): cap regs at 128 total (64 AGPR acc + ~60 VGPR)
// -> 4 blocks/CU resident; cross-block overlap hides the barrier drain (m114).
// MODE 0: bf16 row-major out. 1: K-heads layout. 2: V^T layout.
// MODE 3: f32 out + bias + residual.
template <int MODE>
__global__ __launch_bounds__(256, 4)
void gemm_glds(const u16* __restrict__ A, const u16* __restrict__ Bt,
               void* __restrict__ outp, int K, int ntn,
               const float* __restrict__ bias, const float* __restrict__ resid) {
  __shared__ u16 Alds[128 * 32];
  __shared__ u16 Blds[128 * 32];
  const int tid = threadIdx.x;
  const int wid = tid >> 6, lane = tid & 63;
  const int wm = wid >> 1, wn = wid & 1;
  const int g = lane >> 4, r = lane & 15;

  const int nwg = gridDim.x;
  const int orig = blockIdx.x;
  const int wg = (orig & 7) * (nwg >> 3) + (orig >> 3);  // XCD swizzle (m157)
  const int mt = wg / ntn, nt = wg - mt * ntn;
  const int row0 = mt * 128, col0 = nt * 128;

  // staging map: thread t covers elements [t*8, t*8+8) of each 2048-elem half
  const int erow = tid >> 2, ecol = (tid & 3) * 8;

  f32x4 acc[4][4] = {};

  for (int kt = 0; kt < K; kt += 32) {
    const u16* ag = A + (size_t)(row0 + erow) * K + kt + ecol;
    const u16* bg = Bt + (size_t)(col0 + erow) * K + kt + ecol;
    gll16(ag, &Alds[erow * 32 + ecol]);
    gll16(ag + (size_t)64 * K, &Alds[(erow + 64) * 32 + ecol]);
    gll16(bg, &Blds[erow * 32 + ecol]);
    gll16(bg + (size_t)64 * K, &Blds[(erow + 64) * 32 + ecol]);
    __syncthreads();  // drains vmcnt (global_load_lds) + barrier

    short8 afr[4], bfr[4];
#pragma unroll
    for (int mi = 0; mi < 4; mi++)
      afr[mi] = *(short8*)&Alds[(wm * 64 + mi * 16 + r) * 32 + g * 8];
#pragma unroll
    for (int ni = 0; ni < 4; ni++)
      bfr[ni] = *(short8*)&Blds[(wn * 64 + ni * 16 + r) * 32 + g * 8];
#pragma unroll
    for (int mi = 0; mi < 4; mi++)
#pragma unroll
      for (int ni = 0; ni < 4; ni++)
        acc[mi][ni] = __builtin_amdgcn_mfma_f32_16x16x32_bf16(afr[mi], bfr[ni],
                                                              acc[mi][ni], 0, 0, 0);
    __syncthreads();
  }

  // epilogue: D row = (lane>>4)*4 + i, col = lane&15 (m89-verified layout)
  if constexpr (MODE == 0) {
    u16* O = (u16*)outp;
#pragma unroll
    for (int mi = 0; mi < 4; mi++)
#pragma unroll
      for (int i = 0; i < 4; i++) {
        size_t m = row0 + wm * 64 + mi * 16 + g * 4 + i;
        size_t base = m * HDIM + col0 + wn * 64 + r;
#pragma unroll
        for (int ni = 0; ni < 4; ni++)
          O[base + ni * 16] = f2bf(acc[mi][ni][i]);
      }
  } else if constexpr (MODE == 1 || MODE == 2) {
    u16* O = (u16*)outp;
#pragma unroll
    for (int mi = 0; mi < 4; mi++)
#pragma unroll
      for (int i = 0; i < 4; i++) {
        int m = row0 + wm * 64 + mi * 16 + g * 4 + i;
        int b = m >> 7, skv = m & 127;
#pragma unroll
        for (int ni = 0; ni < 4; ni++) {
          int col = col0 + wn * 64 + ni * 16 + r;
          int hh = col >> 6, d = col & 63;
          size_t addr;
          if constexpr (MODE == 1)
            addr = (((size_t)b * HEADS + hh) * SKV_PAD + skv) * HD + d;
          else
            addr = (((size_t)b * HEADS + hh) * HD + d) * SKV_PAD + skv;
          O[addr] = f2bf(acc[mi][ni][i]);
        }
      }
  } else {
    float* O = (float*)outp;
#pragma unroll
    for (int mi = 0; mi < 4; mi++)
#pragma unroll
      for (int i = 0; i < 4; i++) {
        size_t m = row0 + wm * 64 + mi * 16 + g * 4 + i;
        size_t base = m * HDIM + col0 + wn * 64 + r;
#pragma unroll
        for (int ni = 0; ni < 4; ni++) {
          int col = col0 + wn * 64 + ni * 16 + r;
          O[base + ni * 16] = acc[mi][ni][i] + bias[col] + resid[base + ni * 16];
        }
      }
  }
}

// ---- fused attention: per block = 64 q-rows of one (b,h); 4 waves x 16 rows.
__global__ __launch_bounds__(256, 2)
void attn_kernel(const u16* __restrict__ q, const u16* __restrict__ kh,
                 const u16* __restrict__ vt, u16* __restrict__ o) {
  __shared__ u16 Klds[SKV_T * 72];    // [skv 112][d 64+8 pad]
  __shared__ u16 Vlds[HD * 136];      // [d 64][skv 128+8 pad]
  __shared__ u16 Plds[4 * 16 * 136];  // per-wave P [16][128+8]
  const int tid = threadIdx.x;
  const int wid = tid >> 6, lane = tid & 63;
  const int g = lane >> 4, r = lane & 15;
  const int qt = blockIdx.x;
  const int bh = blockIdx.y;
  const int b = bh / HEADS, h = bh - b * HEADS;

  const u16* kg = kh + (size_t)bh * SKV_PAD * HD;
  for (int i = tid; i < SKV_T * 8; i += 256) {
    int row = i >> 3, c = (i & 7) * 8;
    *(short8*)&Klds[row * 72 + c] = *(const short8*)(kg + row * HD + c);
  }
  const u16* vg = vt + (size_t)bh * HD * SKV_PAD;
  for (int i = tid; i < HD * 16; i += 256) {
    int row = i >> 4, c = (i & 15) * 8;
    *(short8*)&Vlds[row * 136 + c] = *(const short8*)(vg + row * SKV_PAD + c);
  }
  __syncthreads();

  // Q fragments straight from global (scale 1/8 folded into Wq)
  const u16* qg = q + ((size_t)b * SQ + qt * 64 + wid * 16 + r) * HDIM + h * HD + g * 8;
  short8 aq0 = *(const short8*)(qg);
  short8 aq1 = *(const short8*)(qg + 32);

  f32x4 s[7];
#pragma unroll
  for (int nf = 0; nf < 7; nf++) {
    f32x4 z = {0.f, 0.f, 0.f, 0.f};
    short8 k0 = *(short8*)&Klds[(nf * 16 + r) * 72 + g * 8];
    short8 k1 = *(short8*)&Klds[(nf * 16 + r) * 72 + 32 + g * 8];
    z = __builtin_amdgcn_mfma_f32_16x16x32_bf16(aq0, k0, z, 0, 0, 0);
    z = __builtin_amdgcn_mfma_f32_16x16x32_bf16(aq1, k1, z, 0, 0, 0);
    s[nf] = z;
  }

  // zero pad columns 112..127 of this wave's P tile
  {
    short4v z = {0, 0, 0, 0};
    *(short4v*)&Plds[(wid * 16 + r) * 136 + 112 + g * 4] = z;
  }

  // wave-parallel softmax: row (g*4+i) spread over 16 lanes x 7 frags
#pragma unroll
  for (int i = 0; i < 4; i++) {
    float pv[7];
    float mx = -1e30f;
#pragma unroll
    for (int nf = 0; nf < 7; nf++) {
      float v = s[nf][i];
      if (nf == 6 && r >= 13) v = -1e30f;  // cols >= 109 masked
      pv[nf] = v;
      mx = fmaxf(mx, v);
    }
#pragma unroll
    for (int d = 1; d < 16; d <<= 1) mx = fmaxf(mx, __shfl_xor(mx, d, 64));
    float sum = 0.f;
#pragma unroll
    for (int nf = 0; nf < 7; nf++) {
      float e = (nf == 6 && r >= 13) ? 0.f : __expf(pv[nf] - mx);
      pv[nf] = e;
      sum += e;
    }
#pragma unroll
    for (int d = 1; d < 16; d <<= 1) sum += __shfl_xor(sum, d, 64);
    float is = 1.f / sum;
#pragma unroll
    for (int nf = 0; nf < 7; nf++)
      Plds[(wid * 16 + g * 4 + i) * 136 + nf * 16 + r] = f2bf(pv[nf] * is);
  }
  __syncthreads();

  f32x4 oacc[4] = {};
#pragma unroll
  for (int kk = 0; kk < 4; kk++) {
    short8 ap = *(short8*)&Plds[(wid * 16 + r) * 136 + kk * 32 + g * 8];
#pragma unroll
    for (int nf = 0; nf < 4; nf++) {
      short8 bv = *(short8*)&Vlds[(nf * 16 + r) * 136 + kk * 32 + g * 8];
      oacc[nf] = __builtin_amdgcn_mfma_f32_16x16x32_bf16(ap, bv, oacc[nf], 0, 0, 0);
    }
  }
  u16* og = o + ((size_t)b * SQ + qt * 64 + wid * 16) * HDIM + h * HD;
#pragma unroll
  for (int nf = 0; nf < 4; nf++)
#pragma unroll
    for (int i = 0; i < 4; i++)
      og[(size_t)(g * 4 + i) * HDIM + nf * 16 + r] = f2bf(oacc[nf][i]);
}

extern "C" void kernel_launch(void* const* d_in, const int* in_sizes, int n_in,
                              void* d_out, int out_size, void* d_ws, size_t ws_size,
                              hipStream_t stream) {
  const float* hs  = (const float*)d_in[0];
  const float* ehs = (const float*)d_in[1];
  const float* Wq  = (const float*)d_in[2];
  const float* Wk  = (const float*)d_in[3];
  const float* Wv  = (const float*)d_in[4];
  const float* Wo  = (const float*)d_in[5];
  const float* bo  = (const float*)d_in[6];

  char* ws = (char*)d_ws;
  size_t off = 0;
  auto alloc = [&](size_t elems) {
    u16* p = (u16*)(ws + off);
    off += ((elems * 2 + 255) / 256) * 256;
    return p;
  };
  u16* wqt  = alloc((size_t)HDIM * HDIM);
  u16* wot  = alloc((size_t)HDIM * HDIM);
  u16* wkt  = alloc((size_t)HDIM * CDIM);
  u16* wvt  = alloc((size_t)HDIM * CDIM);
  u16* ehsp = alloc((size_t)BB * SKV_PAD * CDIM);
  u16* khb  = alloc((size_t)BB * HEADS * SKV_PAD * HD);
  u16* vtb  = alloc((size_t)BB * HEADS * HD * SKV_PAD);
  u16* qb   = alloc((size_t)BB * SQ * HDIM);
  u16* ao   = alloc((size_t)BB * SQ * HDIM);
  u16* hsb  = ao;  // alias: hsb dead before attention writes ao

  // prep: weight transposes (1/sqrt(64) folded into Wq), encoder pad, hs->bf16
  tcvt<<<dim3(HDIM / 32, HDIM / 32), 256, 0, stream>>>(Wq, wqt, HDIM, HDIM, 0.125f);
  tcvt<<<dim3(HDIM / 32, CDIM / 32), 256, 0, stream>>>(Wk, wkt, CDIM, HDIM, 1.0f);
  tcvt<<<dim3(HDIM / 32, CDIM / 32), 256, 0, stream>>>(Wv, wvt, CDIM, HDIM, 1.0f);
  tcvt<<<dim3(HDIM / 32, HDIM / 32), 256, 0, stream>>>(Wo, wot, HDIM, HDIM, 1.0f);
  ehs_prep<<<dim3((BB * SKV_PAD * CDIM / 4 + 255) / 256), 256, 0, stream>>>(ehs, ehsp);
  hscvt<<<dim3(2048), 256, 0, stream>>>(hs, hsb);

  // K,V projections (M = 1024 padded rows; grid 80 % 8 == 0)
  gemm_glds<1><<<dim3(80), 256, 0, stream>>>(ehsp, wkt, khb, CDIM, 10, nullptr, nullptr);
  gemm_glds<2><<<dim3(80), 256, 0, stream>>>(ehsp, wvt, vtb, CDIM, 10, nullptr, nullptr);
  // Q projection (bf16 A; grid 2560 % 8 == 0)
  gemm_glds<0><<<dim3(2560), 256, 0, stream>>>(hsb, wqt, qb, HDIM, 10, nullptr, nullptr);
  // attention
  attn_kernel<<<dim3(SQ / 64, BB * HEADS), 256, 0, stream>>>(qb, khb, vtb, ao);
  // output projection + bias + f32 residual
  gemm_glds<3><<<dim3(2560), 256, 0, stream>>>(ao, wot, (void*)d_out, HDIM, 10, bo, hs);
}

// Round 4
// 464.097 us; speedup vs baseline: 1.4794x; 1.0487x over previous
//
#include <hip/hip_runtime.h>
#include <hip/hip_bf16.h>

typedef unsigned short u16;
typedef __attribute__((ext_vector_type(8))) short short8;
typedef __attribute__((ext_vector_type(4))) short short4v;
typedef __attribute__((ext_vector_type(4))) float f32x4;

#define HEADS 20
#define HD 64
#define BB 8
#define SQ 4096
#define HDIM 1280
#define SKV 109
#define CDIM 768
#define SKV_PAD 128
#define SKV_T 112

#define SBAR() asm volatile("s_barrier" ::: "memory")

static __device__ __forceinline__ u16 f2bf(float x) {
  union { __hip_bfloat16 h; u16 u; } cv;
  cv.h = __float2bfloat16(x);
  return cv.u;
}

// async global->LDS, 16B per lane (dest = wave-uniform base + lane*16).
static __device__ __forceinline__ void gll16(const void* g, void* l) {
  __builtin_amdgcn_global_load_lds(
      (const __attribute__((address_space(1))) unsigned int*)g,
      (__attribute__((address_space(3))) unsigned int*)l, 16, 0, 0);
}

// ---- prep: out[n][k] = bf16(W[k][n] * scale)  (W is K x N row-major)
__global__ __launch_bounds__(256) void tcvt(const float* __restrict__ W,
                                            u16* __restrict__ out, int K, int N,
                                            float scale) {
  __shared__ float t[32][33];
  int tx = threadIdx.x & 31, ty = threadIdx.x >> 5;
  int n0 = blockIdx.x * 32, k0 = blockIdx.y * 32;
#pragma unroll
  for (int i = 0; i < 32; i += 8)
    t[ty + i][tx] = W[(size_t)(k0 + ty + i) * N + n0 + tx];
  __syncthreads();
#pragma unroll
  for (int i = 0; i < 32; i += 8)
    out[(size_t)(n0 + ty + i) * K + k0 + tx] = f2bf(t[tx][ty + i] * scale);
}

// ---- prep: encoder states f32 (8,109,768) -> bf16 (8,128,768), zero pad rows
__global__ __launch_bounds__(256) void ehs_prep(const float* __restrict__ e,
                                                u16* __restrict__ out) {
  int idx = blockIdx.x * 256 + threadIdx.x;
  if (idx >= BB * SKV_PAD * CDIM / 4) return;
  int c4 = idx * 4;
  int b = c4 / (SKV_PAD * CDIM);
  int rem = c4 - b * (SKV_PAD * CDIM);
  int s = rem / CDIM;
  int c = rem - s * CDIM;
  short4v o = {0, 0, 0, 0};
  if (s < SKV) {
    f32x4 v = *(const f32x4*)(e + ((size_t)b * SKV + s) * CDIM + c);
#pragma unroll
    for (int j = 0; j < 4; j++) o[j] = (short)f2bf(v[j]);
  }
  *(short4v*)&out[c4] = o;
}

// ---- prep: hidden_states f32 -> bf16 (vectorized 8/thread, grid-stride)
__global__ __launch_bounds__(256) void hscvt(const float* __restrict__ in,
                                             u16* __restrict__ out) {
  const size_t total = (size_t)BB * SQ * HDIM;
  size_t step = (size_t)gridDim.x * 256 * 8;
  for (size_t i = ((size_t)blockIdx.x * 256 + threadIdx.x) * 8; i < total;
       i += step) {
    f32x4 a = *(const f32x4*)(in + i);
    f32x4 b = *(const f32x4*)(in + i + 4);
    short8 o;
#pragma unroll
    for (int j = 0; j < 4; j++) {
      o[j] = (short)f2bf(a[j]);
      o[j + 4] = (short)f2bf(b[j]);
    }
    *(short8*)&out[i] = o;
  }
}

// ======================= 256x256 8-phase GEMM (m201 port) ====================
// C = A(MxK) @ Bt(NxK)^T. BK=64, 8 waves (2Mx4N), 512 thr, 128KB LDS dbuf.
// T2: XOR swizzle (row&7)<<3 on LDS elems, applied via pre-swizzled global src
// (global_load_lds writes linearly) and on the ds_read index (involution).
// T3+T4: per-phase {ds_read | stage half-tile | s_barrier | MFMA quadrant},
// vmcnt(4) once per K-tile (2 half-tiles in flight), drain only last 2 tiles.
// T5: setprio(1) around MFMA clusters.

// stage one 16KB half-tile (128 rows x 64 k bf16) into LDS region.
// gbase = global ptr to (row0_of_half, k_tile0); K = row stride in elems.
static __device__ __forceinline__ void stage_half(u16* region,
                                                  const u16* gbase, int K,
                                                  int tid) {
#pragma unroll
  for (int j = 0; j < 2; ++j) {
    int c = tid + j * 512;              // 16B chunk index in region
    int s = c ^ ((c >> 3) & 7);         // inverse-swizzled source chunk
    gll16(gbase + (size_t)(s >> 3) * K + (s & 7) * 8, region + c * 8);
  }
}

// swizzled ds_read of one 16B fragment (8 bf16) at (row, kcol) of a half region
static __device__ __forceinline__ short8 lread(const u16* region, int row,
                                               int kcol) {
  int idx = (row * 64 + kcol) ^ ((row & 7) << 3);
  return *(const short8*)(region + idx);
}

// MODE 0: bf16 row-major out.  MODE 3: f32 out + bias + residual.
template <int MODE>
__global__ __launch_bounds__(512, 2)
void gemm256(const u16* __restrict__ A, const u16* __restrict__ Bt,
             void* __restrict__ outp, int K, int ntn,
             const float* __restrict__ bias, const float* __restrict__ resid) {
  // [buf][A=0/B=1][half][128*64 elems]
  __shared__ u16 lds[2][2][2][8192];
  const int tid = threadIdx.x;
  const int wid = tid >> 6, lane = tid & 63;
  const int wm = wid >> 2, wn = wid & 3;
  const int g = lane >> 4, r = lane & 15;

  const int nwg = gridDim.x;
  const int orig = blockIdx.x;
  const int wg = (orig & 7) * (nwg >> 3) + (orig >> 3);  // XCD swizzle
  const int mt = wg / ntn, nt = wg - mt * ntn;
  const int row0 = mt * 256, col0 = nt * 256;

  const u16* Ag = A + (size_t)row0 * K;
  const u16* Bg = Bt + (size_t)col0 * K;
  const int NT = K >> 6;  // K-tiles of 64

  f32x4 acc[8][4] = {};

  // ---- prologue: t0 fully + t1 B-halves; wait for t0 (newest 4 = t1.B float)
  stage_half(&lds[0][0][0][0], Ag, K, tid);
  stage_half(&lds[0][0][1][0], Ag + (size_t)128 * K, K, tid);
  stage_half(&lds[0][1][0][0], Bg, K, tid);
  stage_half(&lds[0][1][1][0], Bg + (size_t)128 * K, K, tid);
  stage_half(&lds[1][1][0][0], Bg + 64, K, tid);
  stage_half(&lds[1][1][1][0], Bg + (size_t)128 * K + 64, K, tid);
  asm volatile("s_waitcnt vmcnt(4)" ::: "memory");
  SBAR();

  for (int t = 0; t < NT; ++t) {
    const int cur = t & 1, nxt = cur ^ 1;
    const u16* Ac = &lds[cur][0][wm][0];        // this wave's A half region
    const u16* Bc = &lds[cur][1][wn >> 1][0];   // this wave's B half region
    const int brow = (wn & 1) * 64;
    short8 a0[4][2], a1[4][2], b0[2][2], b1[2][2];

    // ---- P1: ds A(mh0) 8 + B(nh0) 4; stage t+1.Ah0; MFMA Q(0,0)
#pragma unroll
    for (int mi = 0; mi < 4; ++mi)
#pragma unroll
      for (int ks = 0; ks < 2; ++ks)
        a0[mi][ks] = lread(Ac, mi * 16 + r, ks * 32 + g * 8);
#pragma unroll
    for (int nf = 0; nf < 2; ++nf)
#pragma unroll
      for (int ks = 0; ks < 2; ++ks)
        b0[nf][ks] = lread(Bc, brow + nf * 16 + r, ks * 32 + g * 8);
    if (t + 1 < NT)
      stage_half(&lds[nxt][0][0][0], Ag + (size_t)(t + 1) * 64, K, tid);
    SBAR();
    __builtin_amdgcn_s_setprio(1);
#pragma unroll
    for (int mi = 0; mi < 4; ++mi)
#pragma unroll
      for (int nf = 0; nf < 2; ++nf)
#pragma unroll
        for (int ks = 0; ks < 2; ++ks)
          acc[mi][nf] = __builtin_amdgcn_mfma_f32_16x16x32_bf16(
              a0[mi][ks], b0[nf][ks], acc[mi][nf], 0, 0, 0);
    __builtin_amdgcn_s_setprio(0);
    SBAR();

    // ---- P2: ds B(nh1) 4; stage t+1.Ah1; MFMA Q(0,1)
#pragma unroll
    for (int nf = 0; nf < 2; ++nf)
#pragma unroll
      for (int ks = 0; ks < 2; ++ks)
        b1[nf][ks] = lread(Bc, brow + 32 + nf * 16 + r, ks * 32 + g * 8);
    if (t + 1 < NT)
      stage_half(&lds[nxt][0][1][0], Ag + (size_t)128 * K + (size_t)(t + 1) * 64,
                 K, tid);
    SBAR();
    __builtin_amdgcn_s_setprio(1);
#pragma unroll
    for (int mi = 0; mi < 4; ++mi)
#pragma unroll
      for (int nf = 0; nf < 2; ++nf)
#pragma unroll
        for (int ks = 0; ks < 2; ++ks)
          acc[mi][2 + nf] = __builtin_amdgcn_mfma_f32_16x16x32_bf16(
              a0[mi][ks], b1[nf][ks], acc[mi][2 + nf], 0, 0, 0);
    __builtin_amdgcn_s_setprio(0);
    SBAR();

    // ---- P3: ds A(mh1) 8; stage t+2.Bh0 (region free after P2); MFMA Q(1,1)
#pragma unroll
    for (int mi = 0; mi < 4; ++mi)
#pragma unroll
      for (int ks = 0; ks < 2; ++ks)
        a1[mi][ks] = lread(Ac, 64 + mi * 16 + r, ks * 32 + g * 8);
    if (t + 2 < NT)
      stage_half(&lds[cur][1][0][0], Bg + (size_t)(t + 2) * 64, K, tid);
    SBAR();
    __builtin_amdgcn_s_setprio(1);
#pragma unroll
    for (int mi = 0; mi < 4; ++mi)
#pragma unroll
      for (int nf = 0; nf < 2; ++nf)
#pragma unroll
        for (int ks = 0; ks < 2; ++ks)
          acc[4 + mi][2 + nf] = __builtin_amdgcn_mfma_f32_16x16x32_bf16(
              a1[mi][ks], b1[nf][ks], acc[4 + mi][2 + nf], 0, 0, 0);
    __builtin_amdgcn_s_setprio(0);
    SBAR();

    // ---- P4: stage t+2.Bh1; counted vmcnt; MFMA Q(1,0)
    if (t + 2 < NT)
      stage_half(&lds[cur][1][1][0], Bg + (size_t)128 * K + (size_t)(t + 2) * 64,
                 K, tid);
    if (t < NT - 2)
      asm volatile("s_waitcnt vmcnt(4)" ::: "memory");
    else
      asm volatile("s_waitcnt vmcnt(0)" ::: "memory");
    SBAR();
    __builtin_amdgcn_s_setprio(1);
#pragma unroll
    for (int mi = 0; mi < 4; ++mi)
#pragma unroll
      for (int nf = 0; nf < 2; ++nf)
#pragma unroll
        for (int ks = 0; ks < 2; ++ks)
          acc[4 + mi][nf] = __builtin_amdgcn_mfma_f32_16x16x32_bf16(
              a1[mi][ks], b0[nf][ks], acc[4 + mi][nf], 0, 0, 0);
    __builtin_amdgcn_s_setprio(0);
    SBAR();
  }

  // ---- epilogue: row = row0+wm*128+am*16+g*4+i, col = col0+wn*64+an*16+r
  if constexpr (MODE == 0) {
    u16* O = (u16*)outp;
#pragma unroll
    for (int am = 0; am < 8; ++am)
#pragma unroll
      for (int i = 0; i < 4; ++i) {
        size_t m = row0 + wm * 128 + am * 16 + g * 4 + i;
        size_t base = m * HDIM + col0 + wn * 64 + r;
#pragma unroll
        for (int an = 0; an < 4; ++an)
          O[base + an * 16] = f2bf(acc[am][an][i]);
      }
  } else {
    float* O = (float*)outp;
#pragma unroll
    for (int am = 0; am < 8; ++am)
#pragma unroll
      for (int i = 0; i < 4; ++i) {
        size_t m = row0 + wm * 128 + am * 16 + g * 4 + i;
        size_t base = m * HDIM + col0 + wn * 64 + r;
#pragma unroll
        for (int an = 0; an < 4; ++an) {
          int col = col0 + wn * 64 + an * 16 + r;
          O[base + an * 16] = acc[am][an][i] + bias[col] + resid[base + an * 16];
        }
      }
  }
}

// ---- m97-structure 128x128 GEMM, kept for the small K/V projections.
// MODE 1: K-heads layout. MODE 2: V^T layout.
template <int MODE>
__global__ __launch_bounds__(256, 4)
void gemm_glds(const u16* __restrict__ A, const u16* __restrict__ Bt,
               void* __restrict__ outp, int K, int ntn) {
  __shared__ u16 Alds[128 * 32];
  __shared__ u16 Blds[128 * 32];
  const int tid = threadIdx.x;
  const int wid = tid >> 6, lane = tid & 63;
  const int wm = wid >> 1, wn = wid & 1;
  const int g = lane >> 4, r = lane & 15;

  const int nwg = gridDim.x;
  const int orig = blockIdx.x;
  const int wg = (orig & 7) * (nwg >> 3) + (orig >> 3);
  const int mt = wg / ntn, nt = wg - mt * ntn;
  const int row0 = mt * 128, col0 = nt * 128;
  const int erow = tid >> 2, ecol = (tid & 3) * 8;

  f32x4 acc[4][4] = {};

  for (int kt = 0; kt < K; kt += 32) {
    const u16* ag = A + (size_t)(row0 + erow) * K + kt + ecol;
    const u16* bg = Bt + (size_t)(col0 + erow) * K + kt + ecol;
    gll16(ag, &Alds[erow * 32 + ecol]);
    gll16(ag + (size_t)64 * K, &Alds[(erow + 64) * 32 + ecol]);
    gll16(bg, &Blds[erow * 32 + ecol]);
    gll16(bg + (size_t)64 * K, &Blds[(erow + 64) * 32 + ecol]);
    __syncthreads();

    short8 afr[4], bfr[4];
#pragma unroll
    for (int mi = 0; mi < 4; mi++)
      afr[mi] = *(short8*)&Alds[(wm * 64 + mi * 16 + r) * 32 + g * 8];
#pragma unroll
    for (int ni = 0; ni < 4; ni++)
      bfr[ni] = *(short8*)&Blds[(wn * 64 + ni * 16 + r) * 32 + g * 8];
#pragma unroll
    for (int mi = 0; mi < 4; mi++)
#pragma unroll
      for (int ni = 0; ni < 4; ni++)
        acc[mi][ni] = __builtin_amdgcn_mfma_f32_16x16x32_bf16(afr[mi], bfr[ni],
                                                              acc[mi][ni], 0, 0, 0);
    __syncthreads();
  }

  u16* O = (u16*)outp;
#pragma unroll
  for (int mi = 0; mi < 4; mi++)
#pragma unroll
    for (int i = 0; i < 4; i++) {
      int m = row0 + wm * 64 + mi * 16 + g * 4 + i;
      int b = m >> 7, skv = m & 127;
#pragma unroll
      for (int ni = 0; ni < 4; ni++) {
        int col = col0 + wn * 64 + ni * 16 + r;
        int hh = col >> 6, d = col & 63;
        size_t addr;
        if constexpr (MODE == 1)
          addr = (((size_t)b * HEADS + hh) * SKV_PAD + skv) * HD + d;
        else
          addr = (((size_t)b * HEADS + hh) * HD + d) * SKV_PAD + skv;
        O[addr] = f2bf(acc[mi][ni][i]);
      }
    }
}

// ---- fused attention: per block = 64 q-rows of one (b,h); 4 waves x 16 rows.
__global__ __launch_bounds__(256, 2)
void attn_kernel(const u16* __restrict__ q, const u16* __restrict__ kh,
                 const u16* __restrict__ vt, u16* __restrict__ o) {
  __shared__ u16 Klds[SKV_T * 72];
  __shared__ u16 Vlds[HD * 136];
  __shared__ u16 Plds[4 * 16 * 136];
  const int tid = threadIdx.x;
  const int wid = tid >> 6, lane = tid & 63;
  const int g = lane >> 4, r = lane & 15;
  const int qt = blockIdx.x;
  const int bh = blockIdx.y;
  const int b = bh / HEADS, h = bh - b * HEADS;

  const u16* kg = kh + (size_t)bh * SKV_PAD * HD;
  for (int i = tid; i < SKV_T * 8; i += 256) {
    int row = i >> 3, c = (i & 7) * 8;
    *(short8*)&Klds[row * 72 + c] = *(const short8*)(kg + row * HD + c);
  }
  const u16* vg = vt + (size_t)bh * HD * SKV_PAD;
  for (int i = tid; i < HD * 16; i += 256) {
    int row = i >> 4, c = (i & 15) * 8;
    *(short8*)&Vlds[row * 136 + c] = *(const short8*)(vg + row * SKV_PAD + c);
  }
  __syncthreads();

  const u16* qg = q + ((size_t)b * SQ + qt * 64 + wid * 16 + r) * HDIM + h * HD + g * 8;
  short8 aq0 = *(const short8*)(qg);
  short8 aq1 = *(const short8*)(qg + 32);

  f32x4 s[7];
#pragma unroll
  for (int nf = 0; nf < 7; nf++) {
    f32x4 z = {0.f, 0.f, 0.f, 0.f};
    short8 k0 = *(short8*)&Klds[(nf * 16 + r) * 72 + g * 8];
    short8 k1 = *(short8*)&Klds[(nf * 16 + r) * 72 + 32 + g * 8];
    z = __builtin_amdgcn_mfma_f32_16x16x32_bf16(aq0, k0, z, 0, 0, 0);
    z = __builtin_amdgcn_mfma_f32_16x16x32_bf16(aq1, k1, z, 0, 0, 0);
    s[nf] = z;
  }

  {
    short4v z = {0, 0, 0, 0};
    *(short4v*)&Plds[(wid * 16 + r) * 136 + 112 + g * 4] = z;
  }

#pragma unroll
  for (int i = 0; i < 4; i++) {
    float pv[7];
    float mx = -1e30f;
#pragma unroll
    for (int nf = 0; nf < 7; nf++) {
      float v = s[nf][i];
      if (nf == 6 && r >= 13) v = -1e30f;
      pv[nf] = v;
      mx = fmaxf(mx, v);
    }
#pragma unroll
    for (int d = 1; d < 16; d <<= 1) mx = fmaxf(mx, __shfl_xor(mx, d, 64));
    float sum = 0.f;
#pragma unroll
    for (int nf = 0; nf < 7; nf++) {
      float e = (nf == 6 && r >= 13) ? 0.f : __expf(pv[nf] - mx);
      pv[nf] = e;
      sum += e;
    }
#pragma unroll
    for (int d = 1; d < 16; d <<= 1) sum += __shfl_xor(sum, d, 64);
    float is = 1.f / sum;
#pragma unroll
    for (int nf = 0; nf < 7; nf++)
      Plds[(wid * 16 + g * 4 + i) * 136 + nf * 16 + r] = f2bf(pv[nf] * is);
  }
  __syncthreads();

  f32x4 oacc[4] = {};
#pragma unroll
  for (int kk = 0; kk < 4; kk++) {
    short8 ap = *(short8*)&Plds[(wid * 16 + r) * 136 + kk * 32 + g * 8];
#pragma unroll
    for (int nf = 0; nf < 4; nf++) {
      short8 bv = *(short8*)&Vlds[(nf * 16 + r) * 136 + kk * 32 + g * 8];
      oacc[nf] = __builtin_amdgcn_mfma_f32_16x16x32_bf16(ap, bv, oacc[nf], 0, 0, 0);
    }
  }
  u16* og = o + ((size_t)b * SQ + qt * 64 + wid * 16) * HDIM + h * HD;
#pragma unroll
  for (int nf = 0; nf < 4; nf++)
#pragma unroll
    for (int i = 0; i < 4; i++)
      og[(size_t)(g * 4 + i) * HDIM + nf * 16 + r] = f2bf(oacc[nf][i]);
}

extern "C" void kernel_launch(void* const* d_in, const int* in_sizes, int n_in,
                              void* d_out, int out_size, void* d_ws, size_t ws_size,
                              hipStream_t stream) {
  const float* hs  = (const float*)d_in[0];
  const float* ehs = (const float*)d_in[1];
  const float* Wq  = (const float*)d_in[2];
  const float* Wk  = (const float*)d_in[3];
  const float* Wv  = (const float*)d_in[4];
  const float* Wo  = (const float*)d_in[5];
  const float* bo  = (const float*)d_in[6];

  char* ws = (char*)d_ws;
  size_t off = 0;
  auto alloc = [&](size_t elems) {
    u16* p = (u16*)(ws + off);
    off += ((elems * 2 + 255) / 256) * 256;
    return p;
  };
  u16* wqt  = alloc((size_t)HDIM * HDIM);
  u16* wot  = alloc((size_t)HDIM * HDIM);
  u16* wkt  = alloc((size_t)HDIM * CDIM);
  u16* wvt  = alloc((size_t)HDIM * CDIM);
  u16* ehsp = alloc((size_t)BB * SKV_PAD * CDIM);
  u16* khb  = alloc((size_t)BB * HEADS * SKV_PAD * HD);
  u16* vtb  = alloc((size_t)BB * HEADS * HD * SKV_PAD);
  u16* qb   = alloc((size_t)BB * SQ * HDIM);
  u16* ao   = alloc((size_t)BB * SQ * HDIM);
  u16* hsb  = ao;  // alias: hsb dead before attention writes ao

  tcvt<<<dim3(HDIM / 32, HDIM / 32), 256, 0, stream>>>(Wq, wqt, HDIM, HDIM, 0.125f);
  tcvt<<<dim3(HDIM / 32, CDIM / 32), 256, 0, stream>>>(Wk, wkt, CDIM, HDIM, 1.0f);
  tcvt<<<dim3(HDIM / 32, CDIM / 32), 256, 0, stream>>>(Wv, wvt, CDIM, HDIM, 1.0f);
  tcvt<<<dim3(HDIM / 32, HDIM / 32), 256, 0, stream>>>(Wo, wot, HDIM, HDIM, 1.0f);
  ehs_prep<<<dim3((BB * SKV_PAD * CDIM / 4 + 255) / 256), 256, 0, stream>>>(ehs, ehsp);
  hscvt<<<dim3(2048), 256, 0, stream>>>(hs, hsb);

  // K,V projections (M = 1024 padded rows; grid 80 % 8 == 0)
  gemm_glds<1><<<dim3(80), 256, 0, stream>>>(ehsp, wkt, khb, CDIM, 10);
  gemm_glds<2><<<dim3(80), 256, 0, stream>>>(ehsp, wvt, vtb, CDIM, 10);
  // Q projection: 256x256 8-phase (grid 128*5 = 640, % 8 == 0)
  gemm256<0><<<dim3(640), 512, 0, stream>>>(hsb, wqt, qb, HDIM, 5, nullptr, nullptr);
  // attention
  attn_kernel<<<dim3(SQ / 64, BB * HEADS), 256, 0, stream>>>(qb, khb, vtb, ao);
  // output projection + bias + f32 residual
  gemm256<3><<<dim3(640), 512, 0, stream>>>(ao, wot, (void*)d_out, HDIM, 5, bo, hs);
}